// Round 2
// baseline (425.080 us; speedup 1.0000x reference)
//
#include <hip/hip_runtime.h>
#include <hip/hip_bf16.h>

typedef unsigned short u16;
typedef __attribute__((ext_vector_type(8))) __bf16 bf16x8;
typedef __attribute__((ext_vector_type(4))) float f32x4;

#define INV_HD  0.03125f
#define INV_SHD 0.17677669529663687f
#define LOG2E   1.4426950408889634f

__device__ __forceinline__ u16 f2b(float f) {
  union { float f; unsigned int i; } v; v.f = f;
  unsigned int x = v.i;
  return (u16)((x + 0x7fffu + ((x >> 16) & 1u)) >> 16);
}
__device__ __forceinline__ bf16x8 ld16(const u16* p) {
  return *reinterpret_cast<const bf16x8*>(p);
}
union U8 { bf16x8 v; u16 s[8]; };
// convert 8 consecutive f32 -> bf16x8 fragment (compiler emits 2x dwordx4)
__device__ __forceinline__ bf16x8 cvt8(const float* p) {
  U8 u;
#pragma unroll
  for (int j = 0; j < 8; ++j) u.s[j] = f2b(p[j]);
  return u.v;
}

// ---------------- weight transpose + f32->bf16: WT[n][k] = W[k][n], K = 256 ----------------
__global__ void kT(const float* __restrict__ W, u16* __restrict__ WT, int N, int total)
{
  int i = blockIdx.x * 256 + threadIdx.x;
  if (i >= total) return;
  int n = i >> 8, k = i & 255;
  WT[i] = f2b(W[(size_t)k * N + n]);
}

// ---------------- QKV projection GEMM: [49152,256](f32) @ [256,768] -> bf16 ----------------
__global__ __launch_bounds__(256) void kQKV(
    const float* __restrict__ xs1, const float* __restrict__ xs2, const float* __restrict__ xq,
    const u16* __restrict__ WT, const float* __restrict__ bias, u16* __restrict__ qkv)
{
  const int tid = threadIdx.x;
  const int lane = tid & 63, wid = tid >> 6;
  const int lr = lane & 15, kg = lane >> 4;
  const int m0 = blockIdx.x * 128 + wid * 32;
  const int n0 = blockIdx.y * 384;

  bf16x8 a[2][8];
#pragma unroll
  for (int mt = 0; mt < 2; ++mt) {
    int row = m0 + mt * 16 + lr;
    int b = row / 6144, r = row - b * 6144;
    const float* src;
    if (r < 4096)      src = xs1 + ((size_t)b * 4096 + r) * 256;
    else if (r < 5120) src = xs2 + ((size_t)b * 1024 + (r - 4096)) * 256;
    else               src = xq  + ((size_t)b * 1024 + (r - 5120)) * 256;
    src += kg * 8;
#pragma unroll
    for (int ks = 0; ks < 8; ++ks) a[mt][ks] = cvt8(src + ks * 32);
  }

  for (int nt = 0; nt < 24; ++nt) {
    const int n = n0 + nt * 16;
    const u16* bp = WT + (size_t)(n + lr) * 256 + kg * 8;
    f32x4 acc0 = {0.f,0.f,0.f,0.f}, acc1 = {0.f,0.f,0.f,0.f};
#pragma unroll
    for (int ks = 0; ks < 8; ++ks) {
      bf16x8 bq = ld16(bp + ks * 32);
      acc0 = __builtin_amdgcn_mfma_f32_16x16x32_bf16(a[0][ks], bq, acc0, 0, 0, 0);
      acc1 = __builtin_amdgcn_mfma_f32_16x16x32_bf16(a[1][ks], bq, acc1, 0, 0, 0);
    }
    float bv = bias[n + lr];
#pragma unroll
    for (int i = 0; i < 4; ++i) {
      int r0 = m0 + kg * 4 + i;
      qkv[(size_t)r0 * 768 + n + lr]        = f2b(acc0[i] + bv);
      qkv[(size_t)(r0 + 16) * 768 + n + lr] = f2b(acc1[i] + bv);
    }
  }
}

// ---------------- windowed self-attention (512 windows, 8 heads) ----------------
__global__ __launch_bounds__(256) void kSelf(
    const u16* __restrict__ qkv, const float* __restrict__ tblg, u16* __restrict__ X)
{
  __shared__ u16 Pl[4][64 * 72];
  __shared__ float tbl[1800];
  const int tid = threadIdx.x;
  for (int i = tid; i < 1800; i += 256) tbl[i] = tblg[i];
  __syncthreads();
  const int lane = tid & 63, wid = tid >> 6;
  const int lr = lane & 15, kg = lane >> 4;
  const int b = blockIdx.x >> 6, wz = blockIdx.x & 63;
  const int wy = wz >> 3, wx = wz & 7;
  const size_t tokbase = (size_t)b * 6144 + wy * 512 + wx * 8;
  const size_t xbase   = (size_t)b * 5120 + wy * 512 + wx * 8;
  u16* P = Pl[wid];

  for (int hh = 0; hh < 2; ++hh) {
    const int h = wid * 2 + hh;
    bf16x8 qf[4], kf[4];
#pragma unroll
    for (int t4 = 0; t4 < 4; ++t4) {
      int t = t4 * 16 + lr;
      size_t row = tokbase + (t >> 3) * 64 + (t & 7);
      const u16* p = qkv + row * 768 + h * 32 + kg * 8;
      qf[t4] = ld16(p);
      kf[t4] = ld16(p + 256);
    }
    f32x4 s[4][4];
#pragma unroll
    for (int qt = 0; qt < 4; ++qt)
#pragma unroll
      for (int kt = 0; kt < 4; ++kt) {
        f32x4 z = {0.f,0.f,0.f,0.f};
        s[qt][kt] = __builtin_amdgcn_mfma_f32_16x16x32_bf16(qf[qt], kf[kt], z, 0, 0, 0);
      }
    // V fragments (issued before softmax so latency hides under VALU work)
    bf16x8 vf[2][2];
#pragma unroll
    for (int dt = 0; dt < 2; ++dt)
#pragma unroll
      for (int ks = 0; ks < 2; ++ks) {
        U8 u;
#pragma unroll
        for (int j = 0; j < 8; ++j) {
          int key = ks * 32 + kg * 8 + j;
          size_t row = tokbase + (key >> 3) * 64 + (key & 7);
          u.s[j] = qkv[row * 768 + 512 + h * 32 + dt * 16 + lr];
        }
        vf[dt][ks] = u.v;
      }
    // bias + softmax (base-2 domain)
#pragma unroll
    for (int qt = 0; qt < 4; ++qt)
#pragma unroll
      for (int i = 0; i < 4; ++i) {
        int q = qt * 16 + kg * 4 + i;
        int qi = q >> 3, qj = q & 7;
#pragma unroll
        for (int kt = 0; kt < 4; ++kt) {
          int k = kt * 16 + lr;
          int idx = (qi - (k >> 3) + 7) * 15 + (qj - (k & 7) + 7);
          s[qt][kt][i] = (s[qt][kt][i] * INV_HD + tbl[idx * 8 + h] * INV_SHD) * LOG2E;
        }
        float mx = fmaxf(fmaxf(s[qt][0][i], s[qt][1][i]), fmaxf(s[qt][2][i], s[qt][3][i]));
#pragma unroll
        for (int d = 1; d < 16; d <<= 1) mx = fmaxf(mx, __shfl_xor(mx, d, 64));
        float sum = 0.f;
#pragma unroll
        for (int kt = 0; kt < 4; ++kt) { float p = exp2f(s[qt][kt][i] - mx); s[qt][kt][i] = p; sum += p; }
#pragma unroll
        for (int d = 1; d < 16; d <<= 1) sum += __shfl_xor(sum, d, 64);
        float inv = 1.f / sum;
#pragma unroll
        for (int kt = 0; kt < 4; ++kt) P[q * 72 + kt * 16 + lr] = f2b(s[qt][kt][i] * inv);
      }
    // PV
    f32x4 o[4][2] = {};
#pragma unroll
    for (int qt = 0; qt < 4; ++qt)
#pragma unroll
      for (int ks = 0; ks < 2; ++ks) {
        bf16x8 pf = ld16(P + (qt * 16 + lr) * 72 + ks * 32 + kg * 8);
        o[qt][0] = __builtin_amdgcn_mfma_f32_16x16x32_bf16(pf, vf[0][ks], o[qt][0], 0, 0, 0);
        o[qt][1] = __builtin_amdgcn_mfma_f32_16x16x32_bf16(pf, vf[1][ks], o[qt][1], 0, 0, 0);
      }
#pragma unroll
    for (int qt = 0; qt < 4; ++qt)
#pragma unroll
      for (int i = 0; i < 4; ++i) {
        int t = qt * 16 + kg * 4 + i;
        size_t xrow = xbase + (t >> 3) * 64 + (t & 7);
#pragma unroll
        for (int dt = 0; dt < 2; ++dt)
          X[xrow * 256 + h * 32 + dt * 16 + lr] = f2b(o[qt][dt][i]);
      }
  }
}

// ---------------- cross attention: xq queries vs [xs2 ; xq] keys ----------------
__global__ __launch_bounds__(256) void kCross(const u16* __restrict__ qkv, u16* __restrict__ X)
{
  __shared__ u16 Pl[4][64 * 72];
  const int tid = threadIdx.x;
  const int lane = tid & 63, wid = tid >> 6;
  const int lr = lane & 15, kg = lane >> 4;
  const int pair = blockIdx.x >> 2, qs = blockIdx.x & 3;
  const int b = pair >> 3, h = pair & 7;
  const int q0 = qs * 256 + wid * 64;
  const size_t qrow0 = (size_t)b * 6144 + 5120;
  const size_t krow0 = (size_t)b * 6144 + 4096;
  u16* P = Pl[wid];

  bf16x8 qf[4];
#pragma unroll
  for (int qt = 0; qt < 4; ++qt)
    qf[qt] = ld16(qkv + (qrow0 + q0 + qt * 16 + lr) * 768 + h * 32 + kg * 8);

  f32x4 o[4][2] = {};
  float m[4][4], l[4][4];
#pragma unroll
  for (int qt = 0; qt < 4; ++qt)
#pragma unroll
    for (int i = 0; i < 4; ++i) { m[qt][i] = -1e30f; l[qt][i] = 0.f; }

  for (int ck = 0; ck < 32; ++ck) {
    const int kc0 = ck * 64;
    f32x4 s[4][4];
#pragma unroll
    for (int kt = 0; kt < 4; ++kt) {
      int key = kc0 + kt * 16 + lr;
      size_t row = (key < 1024) ? (krow0 + key) : (qrow0 + (key - 1024));
      bf16x8 kf = ld16(qkv + row * 768 + 256 + h * 32 + kg * 8);
#pragma unroll
      for (int qt = 0; qt < 4; ++qt) {
        f32x4 z = {0.f,0.f,0.f,0.f};
        s[qt][kt] = __builtin_amdgcn_mfma_f32_16x16x32_bf16(qf[qt], kf, z, 0, 0, 0);
      }
    }
    // V fragments early (overlap with softmax VALU)
    bf16x8 vf[2][2];
#pragma unroll
    for (int dt = 0; dt < 2; ++dt)
#pragma unroll
      for (int ks = 0; ks < 2; ++ks) {
        U8 u;
#pragma unroll
        for (int j = 0; j < 8; ++j) {
          int key = kc0 + ks * 32 + kg * 8 + j;
          size_t row = (key < 1024) ? (krow0 + key) : (qrow0 + (key - 1024));
          u.s[j] = qkv[row * 768 + 512 + h * 32 + dt * 16 + lr];
        }
        vf[dt][ks] = u.v;
      }
    const float sc = INV_SHD * LOG2E;
#pragma unroll
    for (int qt = 0; qt < 4; ++qt)
#pragma unroll
      for (int i = 0; i < 4; ++i) {
        float v0 = s[qt][0][i] * sc, v1 = s[qt][1][i] * sc;
        float v2 = s[qt][2][i] * sc, v3 = s[qt][3][i] * sc;
        float mx = fmaxf(fmaxf(v0, v1), fmaxf(v2, v3));
#pragma unroll
        for (int d = 1; d < 16; d <<= 1) mx = fmaxf(mx, __shfl_xor(mx, d, 64));
        float mn = fmaxf(m[qt][i], mx);
        float sca = exp2f(m[qt][i] - mn);
        float p0 = exp2f(v0 - mn), p1 = exp2f(v1 - mn);
        float p2 = exp2f(v2 - mn), p3 = exp2f(v3 - mn);
        float rs = p0 + p1 + p2 + p3;
#pragma unroll
        for (int d = 1; d < 16; d <<= 1) rs += __shfl_xor(rs, d, 64);
        l[qt][i] = l[qt][i] * sca + rs;
        m[qt][i] = mn;
        o[qt][0][i] *= sca; o[qt][1][i] *= sca;
        int q = qt * 16 + kg * 4 + i;
        P[q * 72 +      lr] = f2b(p0);
        P[q * 72 + 16 + lr] = f2b(p1);
        P[q * 72 + 32 + lr] = f2b(p2);
        P[q * 72 + 48 + lr] = f2b(p3);
      }
#pragma unroll
    for (int qt = 0; qt < 4; ++qt)
#pragma unroll
      for (int ks = 0; ks < 2; ++ks) {
        bf16x8 pf = ld16(P + (qt * 16 + lr) * 72 + ks * 32 + kg * 8);
        o[qt][0] = __builtin_amdgcn_mfma_f32_16x16x32_bf16(pf, vf[0][ks], o[qt][0], 0, 0, 0);
        o[qt][1] = __builtin_amdgcn_mfma_f32_16x16x32_bf16(pf, vf[1][ks], o[qt][1], 0, 0, 0);
      }
  }
#pragma unroll
  for (int qt = 0; qt < 4; ++qt)
#pragma unroll
    for (int i = 0; i < 4; ++i) {
      float inv = 1.f / l[qt][i];
      int q = q0 + qt * 16 + kg * 4 + i;
      size_t xrow = (size_t)b * 5120 + 4096 + q;
#pragma unroll
      for (int dt = 0; dt < 2; ++dt)
        X[xrow * 256 + h * 32 + dt * 16 + lr] = f2b(o[qt][dt][i] * inv);
    }
}

// ---------------- output projection: [40960,256] @ [256,256] -> f32 out ----------------
__global__ __launch_bounds__(256) void kProj(
    const u16* __restrict__ Xin, const u16* __restrict__ WT, const float* __restrict__ bias,
    float* __restrict__ out)
{
  const int tid = threadIdx.x;
  const int lane = tid & 63, wid = tid >> 6;
  const int lr = lane & 15, kg = lane >> 4;
  const int m0 = blockIdx.x * 128 + wid * 32;
  const int n0 = blockIdx.y * 128;
  bf16x8 a[2][8];
#pragma unroll
  for (int mt = 0; mt < 2; ++mt) {
    const u16* src = Xin + (size_t)(m0 + mt * 16 + lr) * 256 + kg * 8;
#pragma unroll
    for (int ks = 0; ks < 8; ++ks) a[mt][ks] = ld16(src + ks * 32);
  }
  for (int nt = 0; nt < 8; ++nt) {
    const int n = n0 + nt * 16;
    const u16* bp = WT + (size_t)(n + lr) * 256 + kg * 8;
    f32x4 acc0 = {0.f,0.f,0.f,0.f}, acc1 = {0.f,0.f,0.f,0.f};
#pragma unroll
    for (int ks = 0; ks < 8; ++ks) {
      bf16x8 bq = ld16(bp + ks * 32);
      acc0 = __builtin_amdgcn_mfma_f32_16x16x32_bf16(a[0][ks], bq, acc0, 0, 0, 0);
      acc1 = __builtin_amdgcn_mfma_f32_16x16x32_bf16(a[1][ks], bq, acc1, 0, 0, 0);
    }
    float bv = bias[n + lr];
#pragma unroll
    for (int i = 0; i < 4; ++i) {
      int r0 = m0 + kg * 4 + i;
      out[(size_t)r0 * 256 + n + lr]        = acc0[i] + bv;
      out[(size_t)(r0 + 16) * 256 + n + lr] = acc1[i] + bv;
    }
  }
}

extern "C" void kernel_launch(void* const* d_in, const int* in_sizes, int n_in,
                              void* d_out, int out_size, void* d_ws, size_t ws_size,
                              hipStream_t stream)
{
  const float* xs1   = (const float*)d_in[0];
  const float* xs2   = (const float*)d_in[1];
  const float* xq    = (const float*)d_in[2];
  const float* Wqkv  = (const float*)d_in[3];
  const float* bqkv  = (const float*)d_in[4];
  const float* Wproj = (const float*)d_in[5];
  const float* bproj = (const float*)d_in[6];
  const float* tbl   = (const float*)d_in[7];

  u16* ws  = (u16*)d_ws;
  u16* qkv = ws;                 // 49152*768 = 37748736 elems (bf16)
  u16* X   = qkv + 37748736;     // 40960*256 = 10485760 elems (bf16)
  u16* WTq = X + 10485760;       // 768*256   =   196608 elems (bf16)
  u16* WTp = WTq + 196608;       // 256*256   =    65536 elems (bf16)

  kT<<<768, 256, 0, stream>>>(Wqkv, WTq, 768, 196608);
  kT<<<256, 256, 0, stream>>>(Wproj, WTp, 256, 65536);
  kQKV<<<dim3(384, 2), 256, 0, stream>>>(xs1, xs2, xq, WTq, bqkv, qkv);
  kSelf<<<512, 256, 0, stream>>>(qkv, tbl, X);
  kCross<<<dim3(256), 256, 0, stream>>>(qkv, X);
  kProj<<<dim3(320, 2), 256, 0, stream>>>(X, WTp, bproj, (float*)d_out);
}

// Round 3
// 297.898 us; speedup vs baseline: 1.4269x; 1.4269x over previous
//
#include <hip/hip_runtime.h>
#include <hip/hip_bf16.h>

typedef unsigned short u16;
typedef __attribute__((ext_vector_type(8))) __bf16 bf16x8;
typedef __attribute__((ext_vector_type(4))) float f32x4;

#define INV_HD  0.03125f
#define INV_SHD 0.17677669529663687f
#define LOG2E   1.4426950408889634f

__device__ __forceinline__ float b2f(u16 u) {
  union { unsigned int i; float f; } v; v.i = ((unsigned int)u) << 16; return v.f;
}
__device__ __forceinline__ u16 f2b(float f) {
  union { float f; unsigned int i; } v; v.f = f;
  unsigned int x = v.i;
  return (u16)((x + 0x7fffu + ((x >> 16) & 1u)) >> 16);
}
__device__ __forceinline__ bf16x8 ld16(const u16* p) {
  return *reinterpret_cast<const bf16x8*>(p);
}
union U8 { bf16x8 v; u16 s[8]; };
__device__ __forceinline__ bf16x8 cvt8(const float* p) {
  U8 u;
#pragma unroll
  for (int j = 0; j < 8; ++j) u.s[j] = f2b(p[j]);
  return u.v;
}

// ---------------- weight transpose + f32->bf16: WT[n][k] = W[k][n], K = 256 ----------------
__global__ void kT(const float* __restrict__ W, u16* __restrict__ WT, int N, int total)
{
  int i = blockIdx.x * 256 + threadIdx.x;
  if (i >= total) return;
  int n = i >> 8, k = i & 255;
  WT[i] = f2b(W[(size_t)k * N + n]);
}

// ---------------- QKV projection GEMM: [49152,256](f32) @ [256,768] -> bf16 ----------------
__global__ __launch_bounds__(256) void kQKV(
    const float* __restrict__ xs1, const float* __restrict__ xs2, const float* __restrict__ xq,
    const u16* __restrict__ WT, const float* __restrict__ bias, u16* __restrict__ qkv)
{
  const int tid = threadIdx.x;
  const int lane = tid & 63, wid = tid >> 6;
  const int lr = lane & 15, kg = lane >> 4;
  const int m0 = blockIdx.x * 128 + wid * 32;
  const int n0 = blockIdx.y * 384;

  bf16x8 a[2][8];
#pragma unroll
  for (int mt = 0; mt < 2; ++mt) {
    int row = m0 + mt * 16 + lr;
    int b = row / 6144, r = row - b * 6144;
    const float* src;
    if (r < 4096)      src = xs1 + ((size_t)b * 4096 + r) * 256;
    else if (r < 5120) src = xs2 + ((size_t)b * 1024 + (r - 4096)) * 256;
    else               src = xq  + ((size_t)b * 1024 + (r - 5120)) * 256;
    src += kg * 8;
#pragma unroll
    for (int ks = 0; ks < 8; ++ks) a[mt][ks] = cvt8(src + ks * 32);
  }

  for (int nt = 0; nt < 24; ++nt) {
    const int n = n0 + nt * 16;
    const u16* bp = WT + (size_t)(n + lr) * 256 + kg * 8;
    f32x4 acc0 = {0.f,0.f,0.f,0.f}, acc1 = {0.f,0.f,0.f,0.f};
#pragma unroll
    for (int ks = 0; ks < 8; ++ks) {
      bf16x8 bq = ld16(bp + ks * 32);
      acc0 = __builtin_amdgcn_mfma_f32_16x16x32_bf16(a[0][ks], bq, acc0, 0, 0, 0);
      acc1 = __builtin_amdgcn_mfma_f32_16x16x32_bf16(a[1][ks], bq, acc1, 0, 0, 0);
    }
    float bv = bias[n + lr];
#pragma unroll
    for (int i = 0; i < 4; ++i) {
      int r0 = m0 + kg * 4 + i;
      qkv[(size_t)r0 * 768 + n + lr]        = f2b(acc0[i] + bv);
      qkv[(size_t)(r0 + 16) * 768 + n + lr] = f2b(acc1[i] + bv);
    }
  }
}

// ---------------- windowed self-attention (512 windows, 8 heads) ----------------
__global__ __launch_bounds__(256) void kSelf(
    const u16* __restrict__ qkv, const float* __restrict__ tblg, u16* __restrict__ X)
{
  __shared__ u16 Pl[4][64 * 72];
  __shared__ float tbl[1800];
  const int tid = threadIdx.x;
  for (int i = tid; i < 1800; i += 256) tbl[i] = tblg[i];
  __syncthreads();
  const int lane = tid & 63, wid = tid >> 6;
  const int lr = lane & 15, kg = lane >> 4;
  const int b = blockIdx.x >> 6, wz = blockIdx.x & 63;
  const int wy = wz >> 3, wx = wz & 7;
  const size_t tokbase = (size_t)b * 6144 + wy * 512 + wx * 8;
  const size_t xbase   = (size_t)b * 5120 + wy * 512 + wx * 8;
  u16* P = Pl[wid];

  for (int hh = 0; hh < 2; ++hh) {
    const int h = wid * 2 + hh;
    bf16x8 qf[4], kf[4];
#pragma unroll
    for (int t4 = 0; t4 < 4; ++t4) {
      int t = t4 * 16 + lr;
      size_t row = tokbase + (t >> 3) * 64 + (t & 7);
      const u16* p = qkv + row * 768 + h * 32 + kg * 8;
      qf[t4] = ld16(p);
      kf[t4] = ld16(p + 256);
    }
    f32x4 s[4][4];
#pragma unroll
    for (int qt = 0; qt < 4; ++qt)
#pragma unroll
      for (int kt = 0; kt < 4; ++kt) {
        f32x4 z = {0.f,0.f,0.f,0.f};
        s[qt][kt] = __builtin_amdgcn_mfma_f32_16x16x32_bf16(qf[qt], kf[kt], z, 0, 0, 0);
      }
    bf16x8 vf[2][2];
#pragma unroll
    for (int dt = 0; dt < 2; ++dt)
#pragma unroll
      for (int ks = 0; ks < 2; ++ks) {
        U8 u;
#pragma unroll
        for (int j = 0; j < 8; ++j) {
          int key = ks * 32 + kg * 8 + j;
          size_t row = tokbase + (key >> 3) * 64 + (key & 7);
          u.s[j] = qkv[row * 768 + 512 + h * 32 + dt * 16 + lr];
        }
        vf[dt][ks] = u.v;
      }
#pragma unroll
    for (int qt = 0; qt < 4; ++qt)
#pragma unroll
      for (int i = 0; i < 4; ++i) {
        int q = qt * 16 + kg * 4 + i;
        int qi = q >> 3, qj = q & 7;
#pragma unroll
        for (int kt = 0; kt < 4; ++kt) {
          int k = kt * 16 + lr;
          int idx = (qi - (k >> 3) + 7) * 15 + (qj - (k & 7) + 7);
          s[qt][kt][i] = (s[qt][kt][i] * INV_HD + tbl[idx * 8 + h] * INV_SHD) * LOG2E;
        }
        float mx = fmaxf(fmaxf(s[qt][0][i], s[qt][1][i]), fmaxf(s[qt][2][i], s[qt][3][i]));
#pragma unroll
        for (int d = 1; d < 16; d <<= 1) mx = fmaxf(mx, __shfl_xor(mx, d, 64));
        float sum = 0.f;
#pragma unroll
        for (int kt = 0; kt < 4; ++kt) { float p = exp2f(s[qt][kt][i] - mx); s[qt][kt][i] = p; sum += p; }
#pragma unroll
        for (int d = 1; d < 16; d <<= 1) sum += __shfl_xor(sum, d, 64);
        float inv = 1.f / sum;
#pragma unroll
        for (int kt = 0; kt < 4; ++kt) P[q * 72 + kt * 16 + lr] = f2b(s[qt][kt][i] * inv);
      }
    f32x4 o[4][2] = {};
#pragma unroll
    for (int qt = 0; qt < 4; ++qt)
#pragma unroll
      for (int ks = 0; ks < 2; ++ks) {
        bf16x8 pf = ld16(P + (qt * 16 + lr) * 72 + ks * 32 + kg * 8);
        o[qt][0] = __builtin_amdgcn_mfma_f32_16x16x32_bf16(pf, vf[0][ks], o[qt][0], 0, 0, 0);
        o[qt][1] = __builtin_amdgcn_mfma_f32_16x16x32_bf16(pf, vf[1][ks], o[qt][1], 0, 0, 0);
      }
#pragma unroll
    for (int qt = 0; qt < 4; ++qt)
#pragma unroll
      for (int i = 0; i < 4; ++i) {
        int t = qt * 16 + kg * 4 + i;
        size_t xrow = xbase + (t >> 3) * 64 + (t & 7);
#pragma unroll
        for (int dt = 0; dt < 2; ++dt)
          X[xrow * 256 + h * 32 + dt * 16 + lr] = f2b(o[qt][dt][i]);
      }
  }
}

// ---------------- cross attention: 1024 blocks, 16 q-rows per wave ----------------
__global__ __launch_bounds__(256, 4) void kCross(const u16* __restrict__ qkv, u16* __restrict__ X)
{
  __shared__ u16 Pl[4][16 * 76];
  const int tid = threadIdx.x;
  const int lane = tid & 63, wid = tid >> 6;
  const int lr = lane & 15, kg = lane >> 4;
  const int b = blockIdx.x >> 3, h = blockIdx.x & 7;
  const int q0 = blockIdx.y * 64 + wid * 16;
  const size_t qrow0 = (size_t)b * 6144 + 5120;
  const size_t krow0 = (size_t)b * 6144 + 4096;
  u16* P = Pl[wid];

  // load Q fragment, pre-scaled by INV_SHD*LOG2E (folds softmax scale into MFMA)
  bf16x8 qf;
  {
    const float sc = INV_SHD * LOG2E;
    U8 u;
    u.v = ld16(qkv + (qrow0 + q0 + lr) * 768 + h * 32 + kg * 8);
#pragma unroll
    for (int j = 0; j < 8; ++j) u.s[j] = f2b(b2f(u.s[j]) * sc);
    qf = u.v;
  }

  f32x4 o0 = {0.f,0.f,0.f,0.f}, o1 = {0.f,0.f,0.f,0.f};
  float m[4] = {-1e30f,-1e30f,-1e30f,-1e30f}, l[4] = {0.f,0.f,0.f,0.f};

#pragma unroll 1
  for (int half = 0; half < 2; ++half) {
    const u16* base = qkv + (half ? qrow0 : krow0) * 768;  // keys 0..1023 local
#pragma unroll 1
    for (int ck = 0; ck < 16; ++ck) {
      const int kc0 = ck * 64;
      f32x4 s[4];
#pragma unroll
      for (int kt = 0; kt < 4; ++kt) {
        bf16x8 kf = ld16(base + (size_t)(kc0 + kt * 16 + lr) * 768 + 256 + h * 32 + kg * 8);
        f32x4 z = {0.f,0.f,0.f,0.f};
        s[kt] = __builtin_amdgcn_mfma_f32_16x16x32_bf16(qf, kf, z, 0, 0, 0);
      }
      // V fragments (uniform base: no region ternary)
      bf16x8 vf[2][2];
#pragma unroll
      for (int dt = 0; dt < 2; ++dt)
#pragma unroll
        for (int ks = 0; ks < 2; ++ks) {
          const u16* vp = base + (size_t)(kc0 + ks * 32 + kg * 8) * 768 + 512 + h * 32 + dt * 16 + lr;
          U8 u;
#pragma unroll
          for (int j = 0; j < 8; ++j) u.s[j] = vp[j * 768];
          vf[dt][ks] = u.v;
        }
      // online softmax (scores already in exp2 domain via prescaled Q)
#pragma unroll
      for (int i = 0; i < 4; ++i) {
        float v0 = s[0][i], v1 = s[1][i], v2 = s[2][i], v3 = s[3][i];
        float mx = fmaxf(fmaxf(v0, v1), fmaxf(v2, v3));
#pragma unroll
        for (int d = 1; d < 16; d <<= 1) mx = fmaxf(mx, __shfl_xor(mx, d, 64));
        float mn = fmaxf(m[i], mx);
        float sca = exp2f(m[i] - mn);
        float p0 = exp2f(v0 - mn), p1 = exp2f(v1 - mn);
        float p2 = exp2f(v2 - mn), p3 = exp2f(v3 - mn);
        float rs = p0 + p1 + p2 + p3;
#pragma unroll
        for (int d = 1; d < 16; d <<= 1) rs += __shfl_xor(rs, d, 64);
        l[i] = l[i] * sca + rs;
        m[i] = mn;
        o0[i] *= sca; o1[i] *= sca;
        const int q = kg * 4 + i;
        P[q * 76      + lr] = f2b(p0);
        P[q * 76 + 16 + lr] = f2b(p1);
        P[q * 76 + 32 + lr] = f2b(p2);
        P[q * 76 + 48 + lr] = f2b(p3);
      }
      // PV
#pragma unroll
      for (int ks = 0; ks < 2; ++ks) {
        bf16x8 pf = ld16(P + lr * 76 + ks * 32 + kg * 8);
        o0 = __builtin_amdgcn_mfma_f32_16x16x32_bf16(pf, vf[0][ks], o0, 0, 0, 0);
        o1 = __builtin_amdgcn_mfma_f32_16x16x32_bf16(pf, vf[1][ks], o1, 0, 0, 0);
      }
    }
  }
#pragma unroll
  for (int i = 0; i < 4; ++i) {
    float inv = 1.f / l[i];
    int q = q0 + kg * 4 + i;
    size_t xrow = (size_t)b * 5120 + 4096 + q;
    X[xrow * 256 + h * 32      + lr] = f2b(o0[i] * inv);
    X[xrow * 256 + h * 32 + 16 + lr] = f2b(o1[i] * inv);
  }
}

// ---------------- output projection: [40960,256] @ [256,256] -> f32 out ----------------
__global__ __launch_bounds__(256) void kProj(
    const u16* __restrict__ Xin, const u16* __restrict__ WT, const float* __restrict__ bias,
    float* __restrict__ out)
{
  const int tid = threadIdx.x;
  const int lane = tid & 63, wid = tid >> 6;
  const int lr = lane & 15, kg = lane >> 4;
  const int m0 = blockIdx.x * 128 + wid * 32;
  const int n0 = blockIdx.y * 128;
  bf16x8 a[2][8];
#pragma unroll
  for (int mt = 0; mt < 2; ++mt) {
    const u16* src = Xin + (size_t)(m0 + mt * 16 + lr) * 256 + kg * 8;
#pragma unroll
    for (int ks = 0; ks < 8; ++ks) a[mt][ks] = ld16(src + ks * 32);
  }
  for (int nt = 0; nt < 8; ++nt) {
    const int n = n0 + nt * 16;
    const u16* bp = WT + (size_t)(n + lr) * 256 + kg * 8;
    f32x4 acc0 = {0.f,0.f,0.f,0.f}, acc1 = {0.f,0.f,0.f,0.f};
#pragma unroll
    for (int ks = 0; ks < 8; ++ks) {
      bf16x8 bq = ld16(bp + ks * 32);
      acc0 = __builtin_amdgcn_mfma_f32_16x16x32_bf16(a[0][ks], bq, acc0, 0, 0, 0);
      acc1 = __builtin_amdgcn_mfma_f32_16x16x32_bf16(a[1][ks], bq, acc1, 0, 0, 0);
    }
    float bv = bias[n + lr];
#pragma unroll
    for (int i = 0; i < 4; ++i) {
      int r0 = m0 + kg * 4 + i;
      out[(size_t)r0 * 256 + n + lr]        = acc0[i] + bv;
      out[(size_t)(r0 + 16) * 256 + n + lr] = acc1[i] + bv;
    }
  }
}

extern "C" void kernel_launch(void* const* d_in, const int* in_sizes, int n_in,
                              void* d_out, int out_size, void* d_ws, size_t ws_size,
                              hipStream_t stream)
{
  const float* xs1   = (const float*)d_in[0];
  const float* xs2   = (const float*)d_in[1];
  const float* xq    = (const float*)d_in[2];
  const float* Wqkv  = (const float*)d_in[3];
  const float* bqkv  = (const float*)d_in[4];
  const float* Wproj = (const float*)d_in[5];
  const float* bproj = (const float*)d_in[6];
  const float* tbl   = (const float*)d_in[7];

  u16* ws  = (u16*)d_ws;
  u16* qkv = ws;                 // 49152*768 = 37748736 elems (bf16)
  u16* X   = qkv + 37748736;     // 40960*256 = 10485760 elems (bf16)
  u16* WTq = X + 10485760;       // 768*256   =   196608 elems (bf16)
  u16* WTp = WTq + 196608;       // 256*256   =    65536 elems (bf16)

  kT<<<768, 256, 0, stream>>>(Wqkv, WTq, 768, 196608);
  kT<<<256, 256, 0, stream>>>(Wproj, WTp, 256, 65536);
  kQKV<<<dim3(384, 2), 256, 0, stream>>>(xs1, xs2, xq, WTq, bqkv, qkv);
  kSelf<<<512, 256, 0, stream>>>(qkv, tbl, X);
  kCross<<<dim3(64, 16), 256, 0, stream>>>(qkv, X);
  kProj<<<dim3(320, 2), 256, 0, stream>>>(X, WTp, bproj, (float*)d_out);
}

// Round 4
// 280.400 us; speedup vs baseline: 1.5160x; 1.0624x over previous
//
#include <hip/hip_runtime.h>
#include <hip/hip_bf16.h>

typedef unsigned short u16;
typedef unsigned int u32;
typedef __attribute__((ext_vector_type(8))) __bf16 bf16x8;
typedef __attribute__((ext_vector_type(4))) float f32x4;

#define INV_HD  0.03125f
#define INV_SHD 0.17677669529663687f
#define LOG2E   1.4426950408889634f

__device__ __forceinline__ float b2f(u16 u) {
  union { u32 i; float f; } v; v.i = ((u32)u) << 16; return v.f;
}
__device__ __forceinline__ u16 f2b(float f) {
  union { float f; u32 i; } v; v.f = f;
  u32 x = v.i;
  return (u16)((x + 0x7fffu + ((x >> 16) & 1u)) >> 16);
}
__device__ __forceinline__ bf16x8 ld16(const u16* p) {
  return *reinterpret_cast<const bf16x8*>(p);
}
union U8 { bf16x8 v; u16 s[8]; };
__device__ __forceinline__ bf16x8 cvt8(const float* p) {
  U8 u;
#pragma unroll
  for (int j = 0; j < 8; ++j) u.s[j] = f2b(p[j]);
  return u.v;
}
// v_cvt_pk_bf16_f32: lo16 = bf16(a), hi16 = bf16(b)
__device__ __forceinline__ u32 cvtpk(float a, float b) {
  u32 r;
  asm("v_cvt_pk_bf16_f32 %0, %1, %2" : "=v"(r) : "v"(a), "v"(b));
  return r;
}

// ---------------- weight transpose + f32->bf16: WT[n][k] = W[k][n], K = 256 ----------------
__global__ void kT(const float* __restrict__ W, u16* __restrict__ WT, int N, int total)
{
  int i = blockIdx.x * 256 + threadIdx.x;
  if (i >= total) return;
  int n = i >> 8, k = i & 255;
  WT[i] = f2b(W[(size_t)k * N + n]);
}

// ---------------- QKV GEMM: [49152,256](f32) @ [256,768]
// Q,K -> qk[row][512] (bf16). V -> transposed buffers VT (cross) / VST (self, window order).
__global__ __launch_bounds__(256) void kQKV(
    const float* __restrict__ xs1, const float* __restrict__ xs2, const float* __restrict__ xq,
    const u16* __restrict__ WT, const float* __restrict__ bias,
    u16* __restrict__ qk, u16* __restrict__ VT, u16* __restrict__ VST)
{
  __shared__ u16 vt[128 * 17];
  const int tid = threadIdx.x;
  const int lane = tid & 63, wid = tid >> 6;
  const int lr = lane & 15, kg = lane >> 4;
  const int m0 = blockIdx.x * 128 + wid * 32;
  const int n0 = blockIdx.y * 384;
  const int m0blk = blockIdx.x * 128;
  const int bb = m0blk / 6144, rloc = m0blk - bb * 6144;

  bf16x8 a[2][8];
#pragma unroll
  for (int mt = 0; mt < 2; ++mt) {
    int row = m0 + mt * 16 + lr;
    int b = row / 6144, r = row - b * 6144;
    const float* src;
    if (r < 4096)      src = xs1 + ((size_t)b * 4096 + r) * 256;
    else if (r < 5120) src = xs2 + ((size_t)b * 1024 + (r - 4096)) * 256;
    else               src = xq  + ((size_t)b * 1024 + (r - 5120)) * 256;
    src += kg * 8;
#pragma unroll
    for (int ks = 0; ks < 8; ++ks) a[mt][ks] = cvt8(src + ks * 32);
  }

  for (int nt = 0; nt < 24; ++nt) {
    const int n = n0 + nt * 16;
    const u16* bp = WT + (size_t)(n + lr) * 256 + kg * 8;
    f32x4 acc0 = {0.f,0.f,0.f,0.f}, acc1 = {0.f,0.f,0.f,0.f};
#pragma unroll
    for (int ks = 0; ks < 8; ++ks) {
      bf16x8 bq = ld16(bp + ks * 32);
      acc0 = __builtin_amdgcn_mfma_f32_16x16x32_bf16(a[0][ks], bq, acc0, 0, 0, 0);
      acc1 = __builtin_amdgcn_mfma_f32_16x16x32_bf16(a[1][ks], bq, acc1, 0, 0, 0);
    }
    float bv = bias[n + lr];
    if (n < 512) {
      // Q,K columns: direct write, stride 512
#pragma unroll
      for (int i = 0; i < 4; ++i) {
        int r0 = m0 + kg * 4 + i;
        qk[(size_t)r0 * 512 + n + lr]        = f2b(acc0[i] + bv);
        qk[(size_t)(r0 + 16) * 512 + n + lr] = f2b(acc1[i] + bv);
      }
    } else {
      // V columns: stage in LDS, transpose, write coalesced to VT / VST
      const int mloc = wid * 32 + kg * 4;
#pragma unroll
      for (int i = 0; i < 4; ++i) {
        vt[(mloc + i) * 17 + lr]      = f2b(acc0[i] + bv);
        vt[(mloc + 16 + i) * 17 + lr] = f2b(acc1[i] + bv);
      }
      __syncthreads();
      {
        const int c = tid >> 4, kchunk = tid & 15;
        const int nc = n + c;                  // global col in [512,768)
        const int hh = (nc - 512) >> 5, dd = (nc - 512) & 31;
        U8 pk;
#pragma unroll
        for (int j = 0; j < 8; ++j) pk.s[j] = vt[(kchunk * 8 + j) * 17 + c];
        u16* dst;
        if (rloc < 4096) {
          int y = (rloc >> 6) + (kchunk >> 3);
          int wkey = ((y >> 3) * 8 + (kchunk & 7)) * 64 + (y & 7) * 8;
          dst = VST + ((size_t)(bb * 8 + hh) * 32 + dd) * 4096 + wkey;
        } else {
          int key0 = (rloc < 5120) ? (rloc - 4096 + kchunk * 8)
                                   : (1024 + rloc - 5120 + kchunk * 8);
          dst = VT + ((size_t)(bb * 8 + hh) * 32 + dd) * 2048 + key0;
        }
        *reinterpret_cast<bf16x8*>(dst) = pk.v;
      }
      __syncthreads();
    }
  }
}

// ---------------- windowed self-attention: 4096 (window,head) units, 1 per wave ----------------
__global__ __launch_bounds__(256, 3) void kSelf(
    const u16* __restrict__ qk, const float* __restrict__ tblg,
    const u16* __restrict__ VST, u16* __restrict__ X)
{
  __shared__ u16 Pl[4][64 * 72];
  __shared__ u16 tbl[1800];
  const int tid = threadIdx.x;
  for (int i = tid; i < 1800; i += 256) tbl[i] = f2b(tblg[i]);
  __syncthreads();
  const int lane = tid & 63, wid = tid >> 6;
  const int lr = lane & 15, kg = lane >> 4;
  const int w = blockIdx.x >> 1;
  const int h = (blockIdx.x & 1) * 4 + wid;
  const int b = w >> 6, wz = w & 63;
  const int wy = wz >> 3, wx = wz & 7;
  const size_t tokbase = (size_t)b * 6144 + wy * 512 + wx * 8;
  const size_t xbase   = (size_t)b * 5120 + wy * 512 + wx * 8;
  u16* P = Pl[wid];

  bf16x8 qf[4], kf[4];
#pragma unroll
  for (int t4 = 0; t4 < 4; ++t4) {
    int t = t4 * 16 + lr;
    size_t row = tokbase + (t >> 3) * 64 + (t & 7);
    const u16* p = qk + row * 512 + h * 32 + kg * 8;
    qf[t4] = ld16(p);
    kf[t4] = ld16(p + 256);
  }
  f32x4 s[4][4];
#pragma unroll
  for (int qt = 0; qt < 4; ++qt)
#pragma unroll
    for (int kt = 0; kt < 4; ++kt) {
      f32x4 z = {0.f,0.f,0.f,0.f};
      s[qt][kt] = __builtin_amdgcn_mfma_f32_16x16x32_bf16(qf[qt], kf[kt], z, 0, 0, 0);
    }
  // V fragments from VST (window-ordered, vectorized)
  bf16x8 vf[2][2];
#pragma unroll
  for (int dt = 0; dt < 2; ++dt)
#pragma unroll
    for (int ks = 0; ks < 2; ++ks)
      vf[dt][ks] = ld16(VST + ((size_t)(b * 8 + h) * 32 + dt * 16 + lr) * 4096
                        + wz * 64 + ks * 32 + kg * 8);
  // bias + softmax (base-2 domain)
#pragma unroll
  for (int qt = 0; qt < 4; ++qt)
#pragma unroll
    for (int i = 0; i < 4; ++i) {
      int q = qt * 16 + kg * 4 + i;
      int qi = q >> 3, qj = q & 7;
#pragma unroll
      for (int kt = 0; kt < 4; ++kt) {
        int k = kt * 16 + lr;
        int idx = (qi - (k >> 3) + 7) * 15 + (qj - (k & 7) + 7);
        s[qt][kt][i] = (s[qt][kt][i] * INV_HD + b2f(tbl[idx * 8 + h]) * INV_SHD) * LOG2E;
      }
      float mx = fmaxf(fmaxf(s[qt][0][i], s[qt][1][i]), fmaxf(s[qt][2][i], s[qt][3][i]));
#pragma unroll
      for (int d = 1; d < 16; d <<= 1) mx = fmaxf(mx, __shfl_xor(mx, d, 64));
      float sum = 0.f;
#pragma unroll
      for (int kt = 0; kt < 4; ++kt) { float p = exp2f(s[qt][kt][i] - mx); s[qt][kt][i] = p; sum += p; }
#pragma unroll
      for (int d = 1; d < 16; d <<= 1) sum += __shfl_xor(sum, d, 64);
      float inv = 1.f / sum;
#pragma unroll
      for (int kt = 0; kt < 4; ++kt) P[q * 72 + kt * 16 + lr] = f2b(s[qt][kt][i] * inv);
    }
  f32x4 o[4][2] = {};
#pragma unroll
  for (int qt = 0; qt < 4; ++qt)
#pragma unroll
    for (int ks = 0; ks < 2; ++ks) {
      bf16x8 pf = ld16(P + (qt * 16 + lr) * 72 + ks * 32 + kg * 8);
      o[qt][0] = __builtin_amdgcn_mfma_f32_16x16x32_bf16(pf, vf[0][ks], o[qt][0], 0, 0, 0);
      o[qt][1] = __builtin_amdgcn_mfma_f32_16x16x32_bf16(pf, vf[1][ks], o[qt][1], 0, 0, 0);
    }
#pragma unroll
  for (int qt = 0; qt < 4; ++qt)
#pragma unroll
    for (int i = 0; i < 4; ++i) {
      int t = qt * 16 + kg * 4 + i;
      size_t xrow = xbase + (t >> 3) * 64 + (t & 7);
#pragma unroll
      for (int dt = 0; dt < 2; ++dt)
        X[xrow * 256 + h * 32 + dt * 16 + lr] = f2b(o[qt][dt][i]);
    }
}

// ---------------- cross attention (swapped QK^T; lane owns a q-row) ----------------
__global__ __launch_bounds__(256, 4) void kCross(
    const u16* __restrict__ qk, const u16* __restrict__ VT, u16* __restrict__ X)
{
  __shared__ u16 Pl[4][16 * 72];
  const int tid = threadIdx.x;
  const int lane = tid & 63, wid = tid >> 6;
  const int lr = lane & 15, kg = lane >> 4;
  const int b = blockIdx.x >> 3, h = blockIdx.x & 7;
  const int q0 = blockIdx.y * 64 + wid * 16;
  const size_t qrow0 = (size_t)b * 6144 + 5120;
  const size_t krow0 = (size_t)b * 6144 + 4096;
  const size_t vtb = (size_t)(b * 8 + h) * 32 * 2048;
  u16* P = Pl[wid];

  // Q as B-fragment (col = q), pre-scaled by INV_SHD*LOG2E
  bf16x8 qf;
  {
    const float sc = INV_SHD * LOG2E;
    U8 u;
    u.v = ld16(qk + (qrow0 + q0 + lr) * 512 + h * 32 + kg * 8);
#pragma unroll
    for (int j = 0; j < 8; ++j) u.s[j] = f2b(b2f(u.s[j]) * sc);
    qf = u.v;
  }

  f32x4 o0 = {0.f,0.f,0.f,0.f}, o1 = {0.f,0.f,0.f,0.f};
  float m = -1e30f, l = 0.f;

#pragma unroll 1
  for (int half = 0; half < 2; ++half) {
    const u16* kbase = qk + (half ? qrow0 : krow0) * 512;
    const int kabs0 = half * 1024;
#pragma unroll 1
    for (int ck = 0; ck < 16; ++ck) {
      const int kc0 = ck * 64;
      // swapped QK^T: lane holds 16 scores of q-row (q0+lr)
      f32x4 st[4];
#pragma unroll
      for (int kt = 0; kt < 4; ++kt) {
        bf16x8 kf = ld16(kbase + (size_t)(kc0 + kt * 16 + lr) * 512 + 256 + h * 32 + kg * 8);
        f32x4 z = {0.f,0.f,0.f,0.f};
        st[kt] = __builtin_amdgcn_mfma_f32_16x16x32_bf16(kf, qf, z, 0, 0, 0);
      }
      // V B-fragments from VT (vectorized)
      bf16x8 vf0[2], vf1[2];
#pragma unroll
      for (int ks = 0; ks < 2; ++ks) {
        size_t ko = (size_t)kabs0 + kc0 + ks * 32 + kg * 8;
        vf0[ks] = ld16(VT + vtb + (size_t)lr * 2048 + ko);
        vf1[ks] = ld16(VT + vtb + (size_t)(16 + lr) * 2048 + ko);
      }
      // in-register row softmax (q = q0+lr), cross-kg reduce with 2 shfls
      float mx = fmaxf(fmaxf(fmaxf(st[0][0], st[0][1]), fmaxf(st[0][2], st[0][3])),
                       fmaxf(fmaxf(st[1][0], st[1][1]), fmaxf(st[1][2], st[1][3])));
      mx = fmaxf(mx, fmaxf(fmaxf(fmaxf(st[2][0], st[2][1]), fmaxf(st[2][2], st[2][3])),
                           fmaxf(fmaxf(st[3][0], st[3][1]), fmaxf(st[3][2], st[3][3]))));
      mx = fmaxf(mx, __shfl_xor(mx, 16, 64));
      mx = fmaxf(mx, __shfl_xor(mx, 32, 64));
      float mn = fmaxf(m, mx);
      float sca = exp2f(m - mn);
      float lsum = 0.f;
      float p[4][4];
#pragma unroll
      for (int kt = 0; kt < 4; ++kt)
#pragma unroll
        for (int i = 0; i < 4; ++i) { float pv = exp2f(st[kt][i] - mn); p[kt][i] = pv; lsum += pv; }
      lsum += __shfl_xor(lsum, 16, 64);
      lsum += __shfl_xor(lsum, 32, 64);
      l = l * sca + lsum;
      m = mn;
      // pack P -> LDS (row q=lr, 64 keys), b64 writes
#pragma unroll
      for (int kt = 0; kt < 4; ++kt) {
        u32 w0 = cvtpk(p[kt][0], p[kt][1]);
        u32 w1 = cvtpk(p[kt][2], p[kt][3]);
        *reinterpret_cast<uint2*>(&P[lr * 72 + kt * 16 + kg * 4]) = make_uint2(w0, w1);
      }
      // rescale o (o rows are q = kg*4+i; sca lives at lane lr'=kg*4+i)
#pragma unroll
      for (int i = 0; i < 4; ++i) {
        float si = __shfl(sca, kg * 4 + i, 16);
        o0[i] *= si; o1[i] *= si;
      }
      // PV
#pragma unroll
      for (int ks = 0; ks < 2; ++ks) {
        bf16x8 pf = ld16(P + lr * 72 + ks * 32 + kg * 8);
        o0 = __builtin_amdgcn_mfma_f32_16x16x32_bf16(pf, vf0[ks], o0, 0, 0, 0);
        o1 = __builtin_amdgcn_mfma_f32_16x16x32_bf16(pf, vf1[ks], o1, 0, 0, 0);
      }
    }
  }
#pragma unroll
  for (int i = 0; i < 4; ++i) {
    float li = __shfl(l, kg * 4 + i, 16);
    float inv = 1.f / li;
    int q = q0 + kg * 4 + i;
    size_t xrow = (size_t)b * 5120 + 4096 + q;
    X[xrow * 256 + h * 32      + lr] = f2b(o0[i] * inv);
    X[xrow * 256 + h * 32 + 16 + lr] = f2b(o1[i] * inv);
  }
}

// ---------------- output projection: [40960,256] @ [256,256] -> f32 out ----------------
__global__ __launch_bounds__(256) void kProj(
    const u16* __restrict__ Xin, const u16* __restrict__ WT, const float* __restrict__ bias,
    float* __restrict__ out)
{
  const int tid = threadIdx.x;
  const int lane = tid & 63, wid = tid >> 6;
  const int lr = lane & 15, kg = lane >> 4;
  const int m0 = blockIdx.x * 128 + wid * 32;
  const int n0 = blockIdx.y * 128;
  bf16x8 a[2][8];
#pragma unroll
  for (int mt = 0; mt < 2; ++mt) {
    const u16* src = Xin + (size_t)(m0 + mt * 16 + lr) * 256 + kg * 8;
#pragma unroll
    for (int ks = 0; ks < 8; ++ks) a[mt][ks] = ld16(src + ks * 32);
  }
  for (int nt = 0; nt < 8; ++nt) {
    const int n = n0 + nt * 16;
    const u16* bp = WT + (size_t)(n + lr) * 256 + kg * 8;
    f32x4 acc0 = {0.f,0.f,0.f,0.f}, acc1 = {0.f,0.f,0.f,0.f};
#pragma unroll
    for (int ks = 0; ks < 8; ++ks) {
      bf16x8 bq = ld16(bp + ks * 32);
      acc0 = __builtin_amdgcn_mfma_f32_16x16x32_bf16(a[0][ks], bq, acc0, 0, 0, 0);
      acc1 = __builtin_amdgcn_mfma_f32_16x16x32_bf16(a[1][ks], bq, acc1, 0, 0, 0);
    }
    float bv = bias[n + lr];
#pragma unroll
    for (int i = 0; i < 4; ++i) {
      int r0 = m0 + kg * 4 + i;
      out[(size_t)r0 * 256 + n + lr]        = acc0[i] + bv;
      out[(size_t)(r0 + 16) * 256 + n + lr] = acc1[i] + bv;
    }
  }
}

extern "C" void kernel_launch(void* const* d_in, const int* in_sizes, int n_in,
                              void* d_out, int out_size, void* d_ws, size_t ws_size,
                              hipStream_t stream)
{
  const float* xs1   = (const float*)d_in[0];
  const float* xs2   = (const float*)d_in[1];
  const float* xq    = (const float*)d_in[2];
  const float* Wqkv  = (const float*)d_in[3];
  const float* bqkv  = (const float*)d_in[4];
  const float* Wproj = (const float*)d_in[5];
  const float* bproj = (const float*)d_in[6];
  const float* tbl   = (const float*)d_in[7];

  u16* ws  = (u16*)d_ws;
  u16* qk  = ws;                 // 49152*512 = 25165824 elems (bf16)
  u16* X   = qk + 25165824;      // 40960*256 = 10485760
  u16* WTq = X + 10485760;       // 768*256   =   196608
  u16* WTp = WTq + 196608;       // 256*256   =    65536
  u16* VT  = WTp + 65536;        // 8*8*32*2048 = 4194304
  u16* VST = VT + 4194304;       // 8*8*32*4096 = 8388608

  kT<<<768, 256, 0, stream>>>(Wqkv, WTq, 768, 196608);
  kT<<<256, 256, 0, stream>>>(Wproj, WTp, 256, 65536);
  kQKV<<<dim3(384, 2), 256, 0, stream>>>(xs1, xs2, xq, WTq, bqkv, qk, VT, VST);
  kSelf<<<1024, 256, 0, stream>>>(qk, tbl, VST, X);
  kCross<<<dim3(64, 16), 256, 0, stream>>>(qk, VT, X);
  kProj<<<dim3(320, 2), 256, 0, stream>>>(X, WTp, bproj, (float*)d_out);
}